// Round 13
// baseline (325.685 us; speedup 1.0000x reference)
//
#include <hip/hip_runtime.h>

#define N_NODES 50000
#define N_EDGES 800000

typedef __attribute__((ext_vector_type(8))) short short8v;
typedef __attribute__((ext_vector_type(4))) float f32x4;

__device__ __forceinline__ ushort bf16hi(float v) {
  return (ushort)(__float_as_uint(v) >> 16);
}

__device__ __forceinline__ void split8(const float v[8], short8v& hh, short8v& ll) {
#pragma unroll
  for (int j = 0; j < 8; ++j) {
    unsigned uv = __float_as_uint(v[j]);
    hh[j] = (short)(uv >> 16);
    float hf = __uint_as_float(uv & 0xFFFF0000u);
    ll[j] = (short)(__float_as_uint(v[j] - hf) >> 16);
  }
}

// ==================== combo1: node_x | count | pack ==========================
#define C1_X 196
#define C1_CNT 3125
#define C1_PACK 120

constexpr int XK_THT = 0;      // 2048
constexpr int XK_PHT = 2048;   // 2048
constexpr int XK_THB = 4096;   // 64
constexpr int XK_PHB = 4160;   // 64
constexpr int XK_SZ  = 4224;   // 16.9 KB

// wp layout (ushort offsets):
//  edge: W1 hi [0,8192) lo [8192,16384) | W2sig(tW2) hi [16384,20480) lo [20480,24576)
//  node: tW0 hi 24576 lo 26624 | pW0 hi 28672 lo 30720 | pW1s1 hi 32768 lo 40960
//        pW2sig hi 49152 lo 53248 | pW3s3 hi 57344 lo 59392 | end 61440
__global__ void __launch_bounds__(256) combo1_kernel(
    const float* __restrict__ x,
    const float* __restrict__ thW, const float* __restrict__ thB,
    const float* __restrict__ phW, const float* __restrict__ phB,
    float* __restrict__ out, float* __restrict__ gp,
    const int* __restrict__ dst, int* __restrict__ counts,
    const float* __restrict__ tW1, const float* __restrict__ tW2,
    const float* __restrict__ tW0, const float* __restrict__ pW0,
    const float* __restrict__ pW1, const float* __restrict__ pW2,
    const float* __restrict__ pW3, ushort* __restrict__ wp) {
  const int b = blockIdx.x;
  const int tid = threadIdx.x;
  if (b < C1_X) {
    __shared__ __align__(16) float sm[XK_SZ];
    for (int t = tid; t < 2048; t += 256) {
      int j = t >> 5, k = t & 31;
      sm[XK_THT + t] = thW[k * 64 + j];
      sm[XK_PHT + t] = phW[k * 64 + j];
    }
    for (int t = tid; t < 64; t += 256) {
      sm[XK_THB + t] = thB[t];
      sm[XK_PHB + t] = phB[t];
    }
    __syncthreads();
    int n = b * 256 + tid;
    if (n >= N_NODES) return;

    float xv[32];
    {
      const float4* p = (const float4*)(x + (long)n * 32);
#pragma unroll
      for (int q = 0; q < 8; ++q) {
        float4 v = p[q];
        xv[q * 4 + 0] = v.x; xv[q * 4 + 1] = v.y;
        xv[q * 4 + 2] = v.z; xv[q * 4 + 3] = v.w;
      }
    }
    float* ao = out + (long)n * 128;
    float* go = gp + (long)n * 128;
    for (int j = 0; j < 64; ++j) {
      float dth = 0.f, dph = 0.f;
#pragma unroll
      for (int k = 0; k < 32; ++k) {
        dth += xv[k] * sm[XK_THT + j * 32 + k];
        dph += xv[k] * sm[XK_PHT + j * 32 + k];
      }
      ao[j] = sm[XK_THB + j] + dth;          // a
      go[j] = sm[XK_PHB + j] + dph - dth;    // g
    }
  } else if (b < C1_X + C1_CNT) {
    int e = (b - C1_X) * 256 + tid;
    if (e < N_EDGES) atomicAdd(&counts[dst[e]], 1);
  } else {
    int t = (b - C1_X - C1_CNT) * 256 + tid;
    if (t >= 30720) return;
    float v;
    int hi_off, lo_off;
    if (t < 8192) {
      int fi = t >> 9, lane = (t >> 3) & 63, j = t & 7;
      int r = fi >> 1, f = fi & 1;
      int k2 = r * 16 + (lane & 15);
      int jg = f * 32 + (lane >> 4) * 8 + j;
      v = tW1[jg * 128 + k2];
      hi_off = t; lo_off = 8192 + t;
    } else if (t < 12288) {
      int t2 = t - 8192;
      int fi = t2 >> 9, lane = (t2 >> 3) & 63, j = t2 & 7;
      int tt = fi >> 2, f2 = fi & 3;
      int cc = tt * 16 + (lane & 15);
      int qq = (lane >> 4) & 3;
      int k2 = f2 * 32 + (j >> 2) * 16 + qq * 4 + (j & 3);
      v = tW2[k2 * 32 + cc];
      hi_off = 16384 + t2; lo_off = 20480 + t2;
    } else if (t < 16384) {
      int t3 = t - 12288;
      const float* M = (t3 < 2048) ? tW0 : pW0;
      int tt3 = t3 & 2047;
      int fi = tt3 >> 9, lane = (tt3 >> 3) & 63, j = tt3 & 7;
      int row = fi * 16 + (lane & 15);
      int k = (lane >> 4) * 8 + j;
      v = M[k * 64 + row];
      hi_off = ((t3 < 2048) ? 24576 : 28672) + tt3;
      lo_off = hi_off + 2048;
    } else if (t < 24576) {
      int t5 = t - 16384;
      int fi = t5 >> 9, lane = (t5 >> 3) & 63, j = t5 & 7;
      int r = fi >> 1, f = fi & 1;
      int row = r * 16 + (lane & 15);
      int sig = 32 * f + 16 * (j >> 2) + 4 * ((lane >> 4) & 3) + (j & 3);
      v = pW1[sig * 128 + row];
      hi_off = 32768 + t5; lo_off = 40960 + t5;
    } else if (t < 28672) {
      int t6 = t - 24576;
      int fi = t6 >> 9, lane = (t6 >> 3) & 63, j = t6 & 7;
      int tt = fi >> 2, f2 = fi & 3;
      int cc = tt * 16 + (lane & 15);
      int qq = (lane >> 4) & 3;
      int k2 = f2 * 32 + (j >> 2) * 16 + qq * 4 + (j & 3);
      v = pW2[k2 * 32 + cc];
      hi_off = 49152 + t6; lo_off = 53248 + t6;
    } else {
      int t7 = t - 28672;
      int fi = t7 >> 9, lane = (t7 >> 3) & 63, j = t7 & 7;
      int row = fi * 16 + (lane & 15);
      int sig = 16 * (j >> 2) + 4 * ((lane >> 4) & 3) + (j & 3);
      v = pW3[sig * 64 + row];
      hi_off = 57344 + t7; lo_off = 59392 + t7;
    }
    ushort h = bf16hi(v);
    float hf = __uint_as_float((unsigned)h << 16);
    ushort l = bf16hi(v - hf);
    wp[hi_off] = h;
    wp[lo_off] = l;
  }
}

// ------------------------------- scan --------------------------------------
#define SCAN_NB ((N_NODES + 1023) / 1024)   // 49

__global__ void __launch_bounds__(1024) scan1_kernel(
    const int* __restrict__ counts, int* __restrict__ offsets,
    int* __restrict__ bsum) {
  __shared__ int wsum[16];
  int t = threadIdx.x, b = blockIdx.x;
  int idx = b * 1024 + t;
  int c = (idx < N_NODES) ? counts[idx] : 0;
  int lane = t & 63, w = t >> 6;
  int v = c;
#pragma unroll
  for (int off = 1; off < 64; off <<= 1) {
    int tt = __shfl_up(v, off);
    if (lane >= off) v += tt;
  }
  if (lane == 63) wsum[w] = v;
  __syncthreads();
  int wpre = 0;
#pragma unroll
  for (int i = 0; i < 16; ++i) {
    int tt = wsum[i];
    if (i < w) wpre += tt;
  }
  int incl = v + wpre;
  if (idx < N_NODES) offsets[idx] = incl - c;   // exclusive-within-block
  if (t == 1023) bsum[b] = incl;                // block total
}

__global__ void __launch_bounds__(1024) scan2_kernel(
    const int* __restrict__ bsum, int* __restrict__ offsets,
    int* __restrict__ counts) {
  __shared__ int sb[SCAN_NB];
  int t = threadIdx.x, b = blockIdx.x;
  if (t < SCAN_NB) sb[t] = bsum[t];
  __syncthreads();
  int bpre = 0;
#pragma unroll
  for (int i = 0; i < SCAN_NB; ++i) {
    int tt = sb[i];
    if (i < b) bpre += tt;
  }
  int idx = b * 1024 + t;
  if (idx < N_NODES) {
    int v = offsets[idx] + bpre;
    offsets[idx] = v;
    counts[idx] = v;          // cursor for scatter
  }
  if (b == 0 && t == 0) offsets[N_NODES] = N_EDGES;
}

// =================== combo2: node_en (MFMA) | scatter ========================
#define C2_EN 391
#define C2_SC 1563

__global__ void __launch_bounds__(512) combo2_kernel(
    const float* __restrict__ en, const ushort* __restrict__ wp,
    const float* __restrict__ pb0, const float* __restrict__ pb1,
    const float* __restrict__ pb2, const float* __restrict__ pb3,
    float* __restrict__ u, float* __restrict__ gp,
    const int* __restrict__ src, const int* __restrict__ dst,
    int* __restrict__ cursor, int2* __restrict__ csr) {
  const int b = blockIdx.x;
  const int tid = threadIdx.x;
  if (b < C2_EN) {
    __shared__ __align__(16) ushort lds[36864];   // 72 KB (node frag block)
    {
      const uint4* s4 = (const uint4*)(wp + 24576);
      uint4* d4 = (uint4*)lds;
      for (int i = tid; i < 4608; i += 512) d4[i] = s4[i];
    }
    __syncthreads();
    const int lane = tid & 63, q = lane >> 4, c = lane & 15, wv = tid >> 6;
    const int n = (b * 8 + wv) * 16 + c;
    const bool valid = n < N_NODES;

    float env[8];
#pragma unroll
    for (int j = 0; j < 8; ++j) env[j] = 0.f;
    if (valid) {
      const float4* p = (const float4*)(en + (long)n * 32 + q * 8);
      float4 e0 = p[0], e1 = p[1];
      env[0] = e0.x; env[1] = e0.y; env[2] = e0.z; env[3] = e0.w;
      env[4] = e1.x; env[5] = e1.y; env[6] = e1.z; env[7] = e1.w;
    }
    short8v beh, bel;
    split8(env, beh, bel);

    const short8v* TW0H = (const short8v*)(lds);
    const short8v* TW0L = (const short8v*)(lds + 2048);
    const short8v* PW0H = (const short8v*)(lds + 4096);
    const short8v* PW0L = (const short8v*)(lds + 6144);
    const short8v* NW1H = (const short8v*)(lds + 8192);
    const short8v* NW1L = (const short8v*)(lds + 16384);
    const short8v* NW2H = (const short8v*)(lds + 24576);
    const short8v* NW2L = (const short8v*)(lds + 28672);
    const short8v* NW3H = (const short8v*)(lds + 32768);
    const short8v* NW3L = (const short8v*)(lds + 34816);

#pragma unroll
    for (int t = 0; t < 4; ++t) {
      f32x4 a = {0.f, 0.f, 0.f, 0.f};
      short8v ah = TW0H[t * 64 + lane], al = TW0L[t * 64 + lane];
      a = __builtin_amdgcn_mfma_f32_16x16x32_bf16(ah, beh, a, 0, 0, 0);
      a = __builtin_amdgcn_mfma_f32_16x16x32_bf16(al, beh, a, 0, 0, 0);
      a = __builtin_amdgcn_mfma_f32_16x16x32_bf16(ah, bel, a, 0, 0, 0);
      if (valid) *(f32x4*)(u + (long)n * 64 + t * 16 + q * 4) = a;
    }

    float h0v[4][4];
#pragma unroll
    for (int t = 0; t < 4; ++t) {
      f32x4 a = *(const f32x4*)(pb0 + t * 16 + q * 4);
      short8v ah = PW0H[t * 64 + lane], al = PW0L[t * 64 + lane];
      a = __builtin_amdgcn_mfma_f32_16x16x32_bf16(ah, beh, a, 0, 0, 0);
      a = __builtin_amdgcn_mfma_f32_16x16x32_bf16(al, beh, a, 0, 0, 0);
      a = __builtin_amdgcn_mfma_f32_16x16x32_bf16(ah, bel, a, 0, 0, 0);
#pragma unroll
      for (int g = 0; g < 4; ++g) h0v[t][g] = fmaxf(a[g], 0.f);
    }

    short8v b1h[2], b1l[2];
#pragma unroll
    for (int f = 0; f < 2; ++f) {
      float tmp[8];
#pragma unroll
      for (int j = 0; j < 8; ++j) tmp[j] = h0v[2 * f + (j >> 2)][j & 3];
      split8(tmp, b1h[f], b1l[f]);
    }

    float h1v[8][4];
#pragma unroll
    for (int r = 0; r < 8; ++r) {
      f32x4 a = *(const f32x4*)(pb1 + r * 16 + q * 4);
#pragma unroll
      for (int f = 0; f < 2; ++f) {
        short8v ah = NW1H[(r * 2 + f) * 64 + lane];
        short8v al = NW1L[(r * 2 + f) * 64 + lane];
        a = __builtin_amdgcn_mfma_f32_16x16x32_bf16(ah, b1h[f], a, 0, 0, 0);
        a = __builtin_amdgcn_mfma_f32_16x16x32_bf16(al, b1h[f], a, 0, 0, 0);
        a = __builtin_amdgcn_mfma_f32_16x16x32_bf16(ah, b1l[f], a, 0, 0, 0);
      }
#pragma unroll
      for (int g = 0; g < 4; ++g) h1v[r][g] = fmaxf(a[g], 0.f);
    }

    short8v b2h[4], b2l[4];
#pragma unroll
    for (int f2 = 0; f2 < 4; ++f2) {
      float tmp[8];
#pragma unroll
      for (int j = 0; j < 8; ++j) tmp[j] = h1v[2 * f2 + (j >> 2)][j & 3];
      split8(tmp, b2h[f2], b2l[f2]);
    }

    float h2v[2][4];
#pragma unroll
    for (int tt = 0; tt < 2; ++tt) {
      f32x4 a = *(const f32x4*)(pb2 + tt * 16 + q * 4);
#pragma unroll
      for (int f2 = 0; f2 < 4; ++f2) {
        short8v ah = NW2H[(tt * 4 + f2) * 64 + lane];
        short8v al = NW2L[(tt * 4 + f2) * 64 + lane];
        a = __builtin_amdgcn_mfma_f32_16x16x32_bf16(ah, b2h[f2], a, 0, 0, 0);
        a = __builtin_amdgcn_mfma_f32_16x16x32_bf16(al, b2h[f2], a, 0, 0, 0);
        a = __builtin_amdgcn_mfma_f32_16x16x32_bf16(ah, b2l[f2], a, 0, 0, 0);
      }
#pragma unroll
      for (int g = 0; g < 4; ++g) h2v[tt][g] = fmaxf(a[g], 0.f);
    }

    short8v b3h, b3l;
    {
      float tmp[8];
#pragma unroll
      for (int j = 0; j < 8; ++j) tmp[j] = h2v[j >> 2][j & 3];
      split8(tmp, b3h, b3l);
    }

#pragma unroll
    for (int t = 0; t < 4; ++t) {
      f32x4 a = *(const f32x4*)(pb3 + t * 16 + q * 4);
      short8v ah = NW3H[t * 64 + lane], al = NW3L[t * 64 + lane];
      a = __builtin_amdgcn_mfma_f32_16x16x32_bf16(ah, b3h, a, 0, 0, 0);
      a = __builtin_amdgcn_mfma_f32_16x16x32_bf16(al, b3h, a, 0, 0, 0);
      a = __builtin_amdgcn_mfma_f32_16x16x32_bf16(ah, b3l, a, 0, 0, 0);
      if (valid) *(f32x4*)(gp + (long)n * 128 + 64 + t * 16 + q * 4) = a;
    }
  } else {
    int e = (b - C2_EN) * 512 + tid;
    if (e >= N_EDGES) return;
    int d = dst[e];
    int slot = atomicAdd(&cursor[d], 1);
    csr[slot] = make_int2(src[e], d);
  }
}

// ====== fused: per-edge theta MLP (MFMA) | edge-independent gather ===========
// blocks [0,6250)       : edge MLP (wave = 16 CSR slots)
// blocks [6250,9375)    : gather (16 nodes/block): x-max -> out[0:64] final;
//                         pen-sum -> out[64:128] PARTIAL (finalize adds W3 term)
#define ME_EDGE 6250
#define ME_GATH 3125

__global__ void __launch_bounds__(512) edge_gather_kernel(
    const float* __restrict__ u,
    const int2* __restrict__ csr,
    const float* __restrict__ b0g, const float* __restrict__ b1g,
    const float* __restrict__ b2g,
    const ushort* __restrict__ wp,
    float* __restrict__ h2sum,
    const int* __restrict__ offsets,
    const float* __restrict__ gp, float* __restrict__ out) {
  __shared__ __align__(16) ushort lds[24576];   // 48 KB (edge branch only)
  if (blockIdx.x >= ME_EDGE) {
    // ---------------- gather branch (no LDS use) ----------------
    int g = blockIdx.x - ME_EDGE;
    int n = g * 16 + (threadIdx.x >> 5);   // 16 nodes * 3125 = 50000 exact
    int l = threadIdx.x & 31;
    int half = l >> 4, j4 = l & 15;
    int off = half * 64 + j4 * 4;
    int o0 = offsets[n], o1 = offsets[n + 1];
    int deg = o1 - o0;

    const float NEG = -3.402823466e38f;
    float4 mx = make_float4(NEG, NEG, NEG, NEG);
    float4 sm4 = make_float4(0.f, 0.f, 0.f, 0.f);
    for (int t = o0; t < o1; ++t) {
      int s = csr[t].x;
      float4 v = *(const float4*)(gp + (long)s * 128 + off);
      mx.x = fmaxf(mx.x, v.x); mx.y = fmaxf(mx.y, v.y);
      mx.z = fmaxf(mx.z, v.z); mx.w = fmaxf(mx.w, v.w);
      sm4.x += v.x; sm4.y += v.y; sm4.z += v.z; sm4.w += v.w;
    }
    float4 r;
    if (half == 0) {
      float4 a = *(const float4*)(out + (long)n * 128 + off);
      bool has = deg > 0;
      r.x = has ? a.x + mx.x : 0.f;
      r.y = has ? a.y + mx.y : 0.f;
      r.z = has ? a.z + mx.z : 0.f;
      r.w = has ? a.w + mx.w : 0.f;
    } else {
      r = sm4;   // partial: finalize adds W3^T h2sum + deg*b3 and divides
    }
    *(float4*)(out + (long)n * 128 + off) = r;
    return;
  }

  // ---------------- edge branch (round-12 body, unchanged) ----------------
  {
    const uint4* s4 = (const uint4*)wp;
    uint4* d4 = (uint4*)lds;
    for (int i = threadIdx.x; i < 3072; i += 512) d4[i] = s4[i];
  }
  __syncthreads();

  // bijective XCD swizzle (nwg=6250, q=781, r=2; m204 form)
  const int orig = blockIdx.x;
  const int xcd = orig & 7, loc = orig >> 3;
  const int blk = (xcd < 2) ? xcd * 782 + loc
                            : 2 * 782 + (xcd - 2) * 781 + loc;

  const int lane = threadIdx.x & 63;
  const int q = lane >> 4, c = lane & 15;
  const int wv = threadIdx.x >> 6;
  const int e = (blk * 8 + wv) * 16 + c;   // exact fit: 6250*128=800000
  const int2 pr = csr[e];
  const int s = pr.x, d = pr.y;

  const short8v* W1HI = (const short8v*)(lds);
  const short8v* W1LO = (const short8v*)(lds + 8192);
  const short8v* W2HI = (const short8v*)(lds + 16384);
  const short8v* W2LO = (const short8v*)(lds + 20480);

  short8v bh0, bl0, bh1, bl1;
  {
    const float* ud = u + (long)d * 64 + q * 8;
    const float* us = u + (long)s * 64 + q * 8;
    const float* bp = b0g + q * 8;
#pragma unroll
    for (int f = 0; f < 2; ++f) {
      float4 d0 = *(const float4*)(ud + f * 32);
      float4 d1 = *(const float4*)(ud + f * 32 + 4);
      float4 s0 = *(const float4*)(us + f * 32);
      float4 s1 = *(const float4*)(us + f * 32 + 4);
      float4 c0 = *(const float4*)(bp + f * 32);
      float4 c1 = *(const float4*)(bp + f * 32 + 4);
      float v[8];
      v[0] = fmaxf(d0.x - s0.x + c0.x, 0.f);
      v[1] = fmaxf(d0.y - s0.y + c0.y, 0.f);
      v[2] = fmaxf(d0.z - s0.z + c0.z, 0.f);
      v[3] = fmaxf(d0.w - s0.w + c0.w, 0.f);
      v[4] = fmaxf(d1.x - s1.x + c1.x, 0.f);
      v[5] = fmaxf(d1.y - s1.y + c1.y, 0.f);
      v[6] = fmaxf(d1.z - s1.z + c1.z, 0.f);
      v[7] = fmaxf(d1.w - s1.w + c1.w, 0.f);
      short8v hh, ll;
      split8(v, hh, ll);
      if (f == 0) { bh0 = hh; bl0 = ll; } else { bh1 = hh; bl1 = ll; }
    }
  }

  f32x4 acc[8];
#pragma unroll
  for (int r = 0; r < 8; ++r)
    acc[r] = *(const f32x4*)(b1g + r * 16 + q * 4);
#pragma unroll
  for (int r = 0; r < 8; ++r) {
    short8v ah0 = W1HI[(2 * r) * 64 + lane];
    short8v ah1 = W1HI[(2 * r + 1) * 64 + lane];
    short8v al0 = W1LO[(2 * r) * 64 + lane];
    short8v al1 = W1LO[(2 * r + 1) * 64 + lane];
    acc[r] = __builtin_amdgcn_mfma_f32_16x16x32_bf16(ah0, bh0, acc[r], 0, 0, 0);
    acc[r] = __builtin_amdgcn_mfma_f32_16x16x32_bf16(ah1, bh1, acc[r], 0, 0, 0);
    acc[r] = __builtin_amdgcn_mfma_f32_16x16x32_bf16(al0, bh0, acc[r], 0, 0, 0);
    acc[r] = __builtin_amdgcn_mfma_f32_16x16x32_bf16(al1, bh1, acc[r], 0, 0, 0);
    acc[r] = __builtin_amdgcn_mfma_f32_16x16x32_bf16(ah0, bl0, acc[r], 0, 0, 0);
    acc[r] = __builtin_amdgcn_mfma_f32_16x16x32_bf16(ah1, bl1, acc[r], 0, 0, 0);
  }
  float h1v[8][4];
#pragma unroll
  for (int r = 0; r < 8; ++r)
#pragma unroll
    for (int g = 0; g < 4; ++g) h1v[r][g] = fmaxf(acc[r][g], 0.f);

  short8v b2h[4], b2l[4];
#pragma unroll
  for (int f2 = 0; f2 < 4; ++f2) {
    float tmp[8];
#pragma unroll
    for (int j = 0; j < 8; ++j) tmp[j] = h1v[2 * f2 + (j >> 2)][j & 3];
    split8(tmp, b2h[f2], b2l[f2]);
  }

  f32x4 a20 = *(const f32x4*)(b2g + q * 4);
  f32x4 a21 = *(const f32x4*)(b2g + 16 + q * 4);
#pragma unroll
  for (int f2 = 0; f2 < 4; ++f2) {
    short8v ah = W2HI[f2 * 64 + lane];
    short8v al = W2LO[f2 * 64 + lane];
    a20 = __builtin_amdgcn_mfma_f32_16x16x32_bf16(ah, b2h[f2], a20, 0, 0, 0);
    a20 = __builtin_amdgcn_mfma_f32_16x16x32_bf16(al, b2h[f2], a20, 0, 0, 0);
    a20 = __builtin_amdgcn_mfma_f32_16x16x32_bf16(ah, b2l[f2], a20, 0, 0, 0);
    short8v ah1 = W2HI[(4 + f2) * 64 + lane];
    short8v al1 = W2LO[(4 + f2) * 64 + lane];
    a21 = __builtin_amdgcn_mfma_f32_16x16x32_bf16(ah1, b2h[f2], a21, 0, 0, 0);
    a21 = __builtin_amdgcn_mfma_f32_16x16x32_bf16(al1, b2h[f2], a21, 0, 0, 0);
    a21 = __builtin_amdgcn_mfma_f32_16x16x32_bf16(ah1, b2l[f2], a21, 0, 0, 0);
  }
  float h2v[8];
#pragma unroll
  for (int g = 0; g < 4; ++g) {
    h2v[g] = fmaxf(a20[g], 0.f);
    h2v[4 + g] = fmaxf(a21[g], 0.f);
  }

  // ---- 16-wide segmented inclusive sum along edge columns ----
  int dp = __shfl_up(d, 1, 16);
  bool head = (c == 0) || (dp != d);
  int seg = head ? c : 0;
#pragma unroll
  for (int off = 1; off < 16; off <<= 1) {
    int t = __shfl_up(seg, off, 16);
    if (c >= off) seg = max(seg, t);
  }
#pragma unroll
  for (int off = 1; off < 16; off <<= 1) {
    bool take = (c - off) >= seg;
#pragma unroll
    for (int k = 0; k < 8; ++k) {
      float t = __shfl_up(h2v[k], off, 16);
      if (take) h2v[k] += t;
    }
  }
  int dn = __shfl_down(d, 1, 16);
  bool tail = (c == 15) || (dn != d);
  if (tail) {
    float* hs = h2sum + (long)d * 32 + q * 4;
#pragma unroll
    for (int g = 0; g < 4; ++g) atomicAdd(&hs[g], h2v[g]);
#pragma unroll
    for (int g = 0; g < 4; ++g) atomicAdd(&hs[16 + g], h2v[4 + g]);
  }
}

// -------------- finalize en: out[64:128] = (ssum + W3^T h2sum + deg*b3)/deg --
// 256 threads = 16 nodes x 16 lanes (4 channels each)
__global__ void __launch_bounds__(256) finalize_kernel(
    const int* __restrict__ offsets, const float* __restrict__ h2sum,
    const float* __restrict__ tW3, const float* __restrict__ tb3,
    float* __restrict__ out) {
  __shared__ float sW3[2048 + 64];
  for (int t = threadIdx.x; t < 2048; t += 256) sW3[t] = tW3[t];
  for (int t = threadIdx.x; t < 64; t += 256) sW3[2048 + t] = tb3[t];
  __syncthreads();
  int n = blockIdx.x * 16 + (threadIdx.x >> 4);
  int j4 = threadIdx.x & 15;
  int jj = j4 * 4;
  int deg = offsets[n + 1] - offsets[n];

  float* po = out + (long)n * 128 + 64 + jj;
  float4 ssum = *(const float4*)po;

  float w30 = 0.f, w31 = 0.f, w32 = 0.f, w33 = 0.f;
  const float* h2r = h2sum + (long)n * 32;
#pragma unroll
  for (int k = 0; k < 32; ++k) {
    float h = h2r[k];
    const float* wrow = &sW3[k * 64 + jj];
    w30 += h * wrow[0]; w31 += h * wrow[1];
    w32 += h * wrow[2]; w33 += h * wrow[3];
  }
  float dg = (float)deg;
  float inv = 1.f / fmaxf(dg, 1.f);
  float4 r;
  r.x = (ssum.x + w30 + dg * sW3[2048 + jj + 0]) * inv;
  r.y = (ssum.y + w31 + dg * sW3[2048 + jj + 1]) * inv;
  r.z = (ssum.z + w32 + dg * sW3[2048 + jj + 2]) * inv;
  r.w = (ssum.w + w33 + dg * sW3[2048 + jj + 3]) * inv;
  *(float4*)po = r;
}

// ---------------------------------- launch -----------------------------------
extern "C" void kernel_launch(void* const* d_in, const int* in_sizes, int n_in,
                              void* d_out, int out_size, void* d_ws,
                              size_t ws_size, hipStream_t stream) {
  const float* x   = (const float*)d_in[0];
  const float* en  = (const float*)d_in[1];
  const int* src   = (const int*)d_in[2];
  const int* dst   = (const int*)d_in[3];
  const float* thW = (const float*)d_in[4];
  const float* thB = (const float*)d_in[5];
  const float* phW = (const float*)d_in[6];
  const float* phB = (const float*)d_in[7];
  const float* tW0 = (const float*)d_in[8];
  const float* tb0 = (const float*)d_in[9];
  const float* tW1 = (const float*)d_in[10];
  const float* tb1 = (const float*)d_in[11];
  const float* tW2 = (const float*)d_in[12];
  const float* tb2 = (const float*)d_in[13];
  const float* tW3 = (const float*)d_in[14];
  const float* tb3 = (const float*)d_in[15];
  const float* pW0 = (const float*)d_in[16];
  const float* pb0 = (const float*)d_in[17];
  const float* pW1 = (const float*)d_in[18];
  const float* pb1 = (const float*)d_in[19];
  const float* pW2 = (const float*)d_in[20];
  const float* pb2 = (const float*)d_in[21];
  const float* pW3 = (const float*)d_in[22];
  const float* pb3 = (const float*)d_in[23];

  float* out = (float*)d_out;
  float* ws  = (float*)d_ws;
  // ws layout (floats): gp[N*128], u[N*64], h2sum[N*32], wpack[30720], ints
  float* gp     = ws;                           // 6,400,000
  float* u      = ws + (long)N_NODES * 128;     // 3,200,000
  float* h2sum  = ws + (long)N_NODES * 192;     // 1,600,000
  float* wpf    = ws + (long)N_NODES * 224;     // 30,720 floats (61440 ushorts)
  ushort* wp    = (ushort*)wpf;
  int* iw       = (int*)(wpf + 30720);
  int2* csr     = (int2*)iw;                    // E pairs (src,dst)
  int* counts   = iw + 2 * N_EDGES;             // N (becomes cursor)
  int* offsets  = counts + N_NODES;             // N+1
  int* bsum     = offsets + N_NODES + 1;        // SCAN_NB
  // total ws ≈ 51.8 MB

  hipMemsetAsync(counts, 0, N_NODES * sizeof(int), stream);
  hipMemsetAsync(h2sum, 0, (size_t)N_NODES * 32 * sizeof(float), stream);
  combo1_kernel<<<C1_X + C1_CNT + C1_PACK, 256, 0, stream>>>(
      x, thW, thB, phW, phB, out, gp, dst, counts,
      tW1, tW2, tW0, pW0, pW1, pW2, pW3, wp);
  scan1_kernel<<<SCAN_NB, 1024, 0, stream>>>(counts, offsets, bsum);
  scan2_kernel<<<SCAN_NB, 1024, 0, stream>>>(bsum, offsets, counts);
  combo2_kernel<<<C2_EN + C2_SC, 512, 0, stream>>>(
      en, wp, pb0, pb1, pb2, pb3, u, gp, src, dst, counts, csr);
  edge_gather_kernel<<<ME_EDGE + ME_GATH, 512, 0, stream>>>(
      u, csr, tb0, tb1, tb2, wp, h2sum, offsets, gp, out);
  finalize_kernel<<<N_NODES / 16, 256, 0, stream>>>(
      offsets, h2sum, tW3, tb3, out);
}

// Round 14
// 325.616 us; speedup vs baseline: 1.0002x; 1.0002x over previous
//
#include <hip/hip_runtime.h>

#define N_NODES 50000
#define N_EDGES 800000

typedef __attribute__((ext_vector_type(8))) short short8v;
typedef __attribute__((ext_vector_type(4))) float f32x4;

__device__ __forceinline__ ushort bf16hi(float v) {
  return (ushort)(__float_as_uint(v) >> 16);
}

__device__ __forceinline__ void split8(const float v[8], short8v& hh, short8v& ll) {
#pragma unroll
  for (int j = 0; j < 8; ++j) {
    unsigned uv = __float_as_uint(v[j]);
    hh[j] = (short)(uv >> 16);
    float hf = __uint_as_float(uv & 0xFFFF0000u);
    ll[j] = (short)(__float_as_uint(v[j] - hf) >> 16);
  }
}

// ==================== combo1: node_x | count | pack ==========================
#define C1_X 196
#define C1_CNT 3125
#define C1_PACK 120

constexpr int XK_THT = 0;      // 2048
constexpr int XK_PHT = 2048;   // 2048
constexpr int XK_THB = 4096;   // 64
constexpr int XK_PHB = 4160;   // 64
constexpr int XK_SZ  = 4224;   // 16.9 KB

// wp layout (ushort offsets):
//  edge: W1 hi [0,8192) lo [8192,16384) | W2sig(tW2) hi [16384,20480) lo [20480,24576)
//  node: tW0 hi 24576 lo 26624 | pW0 hi 28672 lo 30720 | pW1s1 hi 32768 lo 40960
//        pW2sig hi 49152 lo 53248 | pW3s3 hi 57344 lo 59392 | end 61440
__global__ void __launch_bounds__(256) combo1_kernel(
    const float* __restrict__ x,
    const float* __restrict__ thW, const float* __restrict__ thB,
    const float* __restrict__ phW, const float* __restrict__ phB,
    float* __restrict__ out, float* __restrict__ gp,
    const int* __restrict__ dst, int* __restrict__ counts,
    const float* __restrict__ tW1, const float* __restrict__ tW2,
    const float* __restrict__ tW0, const float* __restrict__ pW0,
    const float* __restrict__ pW1, const float* __restrict__ pW2,
    const float* __restrict__ pW3, ushort* __restrict__ wp) {
  const int b = blockIdx.x;
  const int tid = threadIdx.x;
  if (b < C1_X) {
    __shared__ __align__(16) float sm[XK_SZ];
    for (int t = tid; t < 2048; t += 256) {
      int j = t >> 5, k = t & 31;
      sm[XK_THT + t] = thW[k * 64 + j];
      sm[XK_PHT + t] = phW[k * 64 + j];
    }
    for (int t = tid; t < 64; t += 256) {
      sm[XK_THB + t] = thB[t];
      sm[XK_PHB + t] = phB[t];
    }
    __syncthreads();
    int n = b * 256 + tid;
    if (n >= N_NODES) return;

    float xv[32];
    {
      const float4* p = (const float4*)(x + (long)n * 32);
#pragma unroll
      for (int q = 0; q < 8; ++q) {
        float4 v = p[q];
        xv[q * 4 + 0] = v.x; xv[q * 4 + 1] = v.y;
        xv[q * 4 + 2] = v.z; xv[q * 4 + 3] = v.w;
      }
    }
    float* ao = out + (long)n * 128;
    float* go = gp + (long)n * 128;
    for (int j = 0; j < 64; ++j) {
      float dth = 0.f, dph = 0.f;
#pragma unroll
      for (int k = 0; k < 32; ++k) {
        dth += xv[k] * sm[XK_THT + j * 32 + k];
        dph += xv[k] * sm[XK_PHT + j * 32 + k];
      }
      ao[j] = sm[XK_THB + j] + dth;          // a
      go[j] = sm[XK_PHB + j] + dph - dth;    // g
    }
  } else if (b < C1_X + C1_CNT) {
    int e = (b - C1_X) * 256 + tid;
    if (e < N_EDGES) atomicAdd(&counts[dst[e]], 1);
  } else {
    int t = (b - C1_X - C1_CNT) * 256 + tid;
    if (t >= 30720) return;
    float v;
    int hi_off, lo_off;
    if (t < 8192) {
      int fi = t >> 9, lane = (t >> 3) & 63, j = t & 7;
      int r = fi >> 1, f = fi & 1;
      int k2 = r * 16 + (lane & 15);
      int jg = f * 32 + (lane >> 4) * 8 + j;
      v = tW1[jg * 128 + k2];
      hi_off = t; lo_off = 8192 + t;
    } else if (t < 12288) {
      int t2 = t - 8192;
      int fi = t2 >> 9, lane = (t2 >> 3) & 63, j = t2 & 7;
      int tt = fi >> 2, f2 = fi & 3;
      int cc = tt * 16 + (lane & 15);
      int qq = (lane >> 4) & 3;
      int k2 = f2 * 32 + (j >> 2) * 16 + qq * 4 + (j & 3);
      v = tW2[k2 * 32 + cc];
      hi_off = 16384 + t2; lo_off = 20480 + t2;
    } else if (t < 16384) {
      int t3 = t - 12288;
      const float* M = (t3 < 2048) ? tW0 : pW0;
      int tt3 = t3 & 2047;
      int fi = tt3 >> 9, lane = (tt3 >> 3) & 63, j = tt3 & 7;
      int row = fi * 16 + (lane & 15);
      int k = (lane >> 4) * 8 + j;
      v = M[k * 64 + row];
      hi_off = ((t3 < 2048) ? 24576 : 28672) + tt3;
      lo_off = hi_off + 2048;
    } else if (t < 24576) {
      int t5 = t - 16384;
      int fi = t5 >> 9, lane = (t5 >> 3) & 63, j = t5 & 7;
      int r = fi >> 1, f = fi & 1;
      int row = r * 16 + (lane & 15);
      int sig = 32 * f + 16 * (j >> 2) + 4 * ((lane >> 4) & 3) + (j & 3);
      v = pW1[sig * 128 + row];
      hi_off = 32768 + t5; lo_off = 40960 + t5;
    } else if (t < 28672) {
      int t6 = t - 24576;
      int fi = t6 >> 9, lane = (t6 >> 3) & 63, j = t6 & 7;
      int tt = fi >> 2, f2 = fi & 3;
      int cc = tt * 16 + (lane & 15);
      int qq = (lane >> 4) & 3;
      int k2 = f2 * 32 + (j >> 2) * 16 + qq * 4 + (j & 3);
      v = pW2[k2 * 32 + cc];
      hi_off = 49152 + t6; lo_off = 53248 + t6;
    } else {
      int t7 = t - 28672;
      int fi = t7 >> 9, lane = (t7 >> 3) & 63, j = t7 & 7;
      int row = fi * 16 + (lane & 15);
      int sig = 16 * (j >> 2) + 4 * ((lane >> 4) & 3) + (j & 3);
      v = pW3[sig * 64 + row];
      hi_off = 57344 + t7; lo_off = 59392 + t7;
    }
    ushort h = bf16hi(v);
    float hf = __uint_as_float((unsigned)h << 16);
    ushort l = bf16hi(v - hf);
    wp[hi_off] = h;
    wp[lo_off] = l;
  }
}

// ------------------------------- scan --------------------------------------
#define SCAN_NB ((N_NODES + 1023) / 1024)   // 49

__global__ void __launch_bounds__(1024) scan1_kernel(
    const int* __restrict__ counts, int* __restrict__ offsets,
    int* __restrict__ bsum) {
  __shared__ int wsum[16];
  int t = threadIdx.x, b = blockIdx.x;
  int idx = b * 1024 + t;
  int c = (idx < N_NODES) ? counts[idx] : 0;
  int lane = t & 63, w = t >> 6;
  int v = c;
#pragma unroll
  for (int off = 1; off < 64; off <<= 1) {
    int tt = __shfl_up(v, off);
    if (lane >= off) v += tt;
  }
  if (lane == 63) wsum[w] = v;
  __syncthreads();
  int wpre = 0;
#pragma unroll
  for (int i = 0; i < 16; ++i) {
    int tt = wsum[i];
    if (i < w) wpre += tt;
  }
  int incl = v + wpre;
  if (idx < N_NODES) offsets[idx] = incl - c;   // exclusive-within-block
  if (t == 1023) bsum[b] = incl;                // block total
}

__global__ void __launch_bounds__(1024) scan2_kernel(
    const int* __restrict__ bsum, int* __restrict__ offsets,
    int* __restrict__ counts) {
  __shared__ int sb[SCAN_NB];
  int t = threadIdx.x, b = blockIdx.x;
  if (t < SCAN_NB) sb[t] = bsum[t];
  __syncthreads();
  int bpre = 0;
#pragma unroll
  for (int i = 0; i < SCAN_NB; ++i) {
    int tt = sb[i];
    if (i < b) bpre += tt;
  }
  int idx = b * 1024 + t;
  if (idx < N_NODES) {
    int v = offsets[idx] + bpre;
    offsets[idx] = v;
    counts[idx] = v;          // cursor for scatter
  }
  if (b == 0 && t == 0) offsets[N_NODES] = N_EDGES;
}

// =================== combo2: node_en (MFMA) | scatter ========================
#define C2_EN 391
#define C2_SC 1563

__global__ void __launch_bounds__(512) combo2_kernel(
    const float* __restrict__ en, const ushort* __restrict__ wp,
    const float* __restrict__ pb0, const float* __restrict__ pb1,
    const float* __restrict__ pb2, const float* __restrict__ pb3,
    float* __restrict__ u, float* __restrict__ gp,
    const int* __restrict__ src, const int* __restrict__ dst,
    int* __restrict__ cursor, int2* __restrict__ csr) {
  const int b = blockIdx.x;
  const int tid = threadIdx.x;
  if (b < C2_EN) {
    __shared__ __align__(16) ushort lds[36864];   // 72 KB (node frag block)
    {
      const uint4* s4 = (const uint4*)(wp + 24576);
      uint4* d4 = (uint4*)lds;
      for (int i = tid; i < 4608; i += 512) d4[i] = s4[i];
    }
    __syncthreads();
    const int lane = tid & 63, q = lane >> 4, c = lane & 15, wv = tid >> 6;
    const int n = (b * 8 + wv) * 16 + c;
    const bool valid = n < N_NODES;

    float env[8];
#pragma unroll
    for (int j = 0; j < 8; ++j) env[j] = 0.f;
    if (valid) {
      const float4* p = (const float4*)(en + (long)n * 32 + q * 8);
      float4 e0 = p[0], e1 = p[1];
      env[0] = e0.x; env[1] = e0.y; env[2] = e0.z; env[3] = e0.w;
      env[4] = e1.x; env[5] = e1.y; env[6] = e1.z; env[7] = e1.w;
    }
    short8v beh, bel;
    split8(env, beh, bel);

    const short8v* TW0H = (const short8v*)(lds);
    const short8v* TW0L = (const short8v*)(lds + 2048);
    const short8v* PW0H = (const short8v*)(lds + 4096);
    const short8v* PW0L = (const short8v*)(lds + 6144);
    const short8v* NW1H = (const short8v*)(lds + 8192);
    const short8v* NW1L = (const short8v*)(lds + 16384);
    const short8v* NW2H = (const short8v*)(lds + 24576);
    const short8v* NW2L = (const short8v*)(lds + 28672);
    const short8v* NW3H = (const short8v*)(lds + 32768);
    const short8v* NW3L = (const short8v*)(lds + 34816);

#pragma unroll
    for (int t = 0; t < 4; ++t) {
      f32x4 a = {0.f, 0.f, 0.f, 0.f};
      short8v ah = TW0H[t * 64 + lane], al = TW0L[t * 64 + lane];
      a = __builtin_amdgcn_mfma_f32_16x16x32_bf16(ah, beh, a, 0, 0, 0);
      a = __builtin_amdgcn_mfma_f32_16x16x32_bf16(al, beh, a, 0, 0, 0);
      a = __builtin_amdgcn_mfma_f32_16x16x32_bf16(ah, bel, a, 0, 0, 0);
      if (valid) *(f32x4*)(u + (long)n * 64 + t * 16 + q * 4) = a;
    }

    float h0v[4][4];
#pragma unroll
    for (int t = 0; t < 4; ++t) {
      f32x4 a = *(const f32x4*)(pb0 + t * 16 + q * 4);
      short8v ah = PW0H[t * 64 + lane], al = PW0L[t * 64 + lane];
      a = __builtin_amdgcn_mfma_f32_16x16x32_bf16(ah, beh, a, 0, 0, 0);
      a = __builtin_amdgcn_mfma_f32_16x16x32_bf16(al, beh, a, 0, 0, 0);
      a = __builtin_amdgcn_mfma_f32_16x16x32_bf16(ah, bel, a, 0, 0, 0);
#pragma unroll
      for (int g = 0; g < 4; ++g) h0v[t][g] = fmaxf(a[g], 0.f);
    }

    short8v b1h[2], b1l[2];
#pragma unroll
    for (int f = 0; f < 2; ++f) {
      float tmp[8];
#pragma unroll
      for (int j = 0; j < 8; ++j) tmp[j] = h0v[2 * f + (j >> 2)][j & 3];
      split8(tmp, b1h[f], b1l[f]);
    }

    float h1v[8][4];
#pragma unroll
    for (int r = 0; r < 8; ++r) {
      f32x4 a = *(const f32x4*)(pb1 + r * 16 + q * 4);
#pragma unroll
      for (int f = 0; f < 2; ++f) {
        short8v ah = NW1H[(r * 2 + f) * 64 + lane];
        short8v al = NW1L[(r * 2 + f) * 64 + lane];
        a = __builtin_amdgcn_mfma_f32_16x16x32_bf16(ah, b1h[f], a, 0, 0, 0);
        a = __builtin_amdgcn_mfma_f32_16x16x32_bf16(al, b1h[f], a, 0, 0, 0);
        a = __builtin_amdgcn_mfma_f32_16x16x32_bf16(ah, b1l[f], a, 0, 0, 0);
      }
#pragma unroll
      for (int g = 0; g < 4; ++g) h1v[r][g] = fmaxf(a[g], 0.f);
    }

    short8v b2h[4], b2l[4];
#pragma unroll
    for (int f2 = 0; f2 < 4; ++f2) {
      float tmp[8];
#pragma unroll
      for (int j = 0; j < 8; ++j) tmp[j] = h1v[2 * f2 + (j >> 2)][j & 3];
      split8(tmp, b2h[f2], b2l[f2]);
    }

    float h2v[2][4];
#pragma unroll
    for (int tt = 0; tt < 2; ++tt) {
      f32x4 a = *(const f32x4*)(pb2 + tt * 16 + q * 4);
#pragma unroll
      for (int f2 = 0; f2 < 4; ++f2) {
        short8v ah = NW2H[(tt * 4 + f2) * 64 + lane];
        short8v al = NW2L[(tt * 4 + f2) * 64 + lane];
        a = __builtin_amdgcn_mfma_f32_16x16x32_bf16(ah, b2h[f2], a, 0, 0, 0);
        a = __builtin_amdgcn_mfma_f32_16x16x32_bf16(al, b2h[f2], a, 0, 0, 0);
        a = __builtin_amdgcn_mfma_f32_16x16x32_bf16(ah, b2l[f2], a, 0, 0, 0);
      }
#pragma unroll
      for (int g = 0; g < 4; ++g) h2v[tt][g] = fmaxf(a[g], 0.f);
    }

    short8v b3h, b3l;
    {
      float tmp[8];
#pragma unroll
      for (int j = 0; j < 8; ++j) tmp[j] = h2v[j >> 2][j & 3];
      split8(tmp, b3h, b3l);
    }

#pragma unroll
    for (int t = 0; t < 4; ++t) {
      f32x4 a = *(const f32x4*)(pb3 + t * 16 + q * 4);
      short8v ah = NW3H[t * 64 + lane], al = NW3L[t * 64 + lane];
      a = __builtin_amdgcn_mfma_f32_16x16x32_bf16(ah, b3h, a, 0, 0, 0);
      a = __builtin_amdgcn_mfma_f32_16x16x32_bf16(al, b3h, a, 0, 0, 0);
      a = __builtin_amdgcn_mfma_f32_16x16x32_bf16(ah, b3l, a, 0, 0, 0);
      if (valid) *(f32x4*)(gp + (long)n * 128 + 64 + t * 16 + q * 4) = a;
    }
  } else {
    int e = (b - C2_EN) * 512 + tid;
    if (e >= N_EDGES) return;
    int d = dst[e];
    int slot = atomicAdd(&cursor[d], 1);
    csr[slot] = make_int2(src[e], d);
  }
}

// ----------- per-edge theta MLP (layers 1,2) via split-bf16 MFMA -------------
// 1024-thread blocks: 16 waves x 16 edges = 256 edges/block, 3125 blocks exact.
// LDS 48KB x 2 blocks/CU = 96KB; VGPR 64 -> 32 waves/CU (full occupancy cap).
__global__ void __launch_bounds__(1024) mlp_edge_kernel(
    const float* __restrict__ u,
    const int2* __restrict__ csr,
    const float* __restrict__ b0g, const float* __restrict__ b1g,
    const float* __restrict__ b2g,
    const ushort* __restrict__ wp,
    float* __restrict__ h2sum) {
  __shared__ __align__(16) ushort lds[24576];   // 48 KB
  {
    const uint4* s4 = (const uint4*)wp;
    uint4* d4 = (uint4*)lds;
    for (int i = threadIdx.x; i < 3072; i += 1024) d4[i] = s4[i];
  }
  __syncthreads();

  // bijective XCD swizzle (nwg=3125, q=390, r=5; m204 form)
  const int orig = blockIdx.x;
  const int xcd = orig & 7, loc = orig >> 3;
  const int blk = (xcd < 5) ? xcd * 391 + loc
                            : 5 * 391 + (xcd - 5) * 390 + loc;

  const int lane = threadIdx.x & 63;
  const int q = lane >> 4, c = lane & 15;
  const int wv = threadIdx.x >> 6;
  const int e = (blk * 16 + wv) * 16 + c;   // exact fit: 3125*256=800000
  const int2 pr = csr[e];
  const int s = pr.x, d = pr.y;

  const short8v* W1HI = (const short8v*)(lds);
  const short8v* W1LO = (const short8v*)(lds + 8192);
  const short8v* W2HI = (const short8v*)(lds + 16384);
  const short8v* W2LO = (const short8v*)(lds + 20480);

  short8v bh0, bl0, bh1, bl1;
  {
    const float* ud = u + (long)d * 64 + q * 8;
    const float* us = u + (long)s * 64 + q * 8;
    const float* bp = b0g + q * 8;
#pragma unroll
    for (int f = 0; f < 2; ++f) {
      float4 d0 = *(const float4*)(ud + f * 32);
      float4 d1 = *(const float4*)(ud + f * 32 + 4);
      float4 s0 = *(const float4*)(us + f * 32);
      float4 s1 = *(const float4*)(us + f * 32 + 4);
      float4 c0 = *(const float4*)(bp + f * 32);
      float4 c1 = *(const float4*)(bp + f * 32 + 4);
      float v[8];
      v[0] = fmaxf(d0.x - s0.x + c0.x, 0.f);
      v[1] = fmaxf(d0.y - s0.y + c0.y, 0.f);
      v[2] = fmaxf(d0.z - s0.z + c0.z, 0.f);
      v[3] = fmaxf(d0.w - s0.w + c0.w, 0.f);
      v[4] = fmaxf(d1.x - s1.x + c1.x, 0.f);
      v[5] = fmaxf(d1.y - s1.y + c1.y, 0.f);
      v[6] = fmaxf(d1.z - s1.z + c1.z, 0.f);
      v[7] = fmaxf(d1.w - s1.w + c1.w, 0.f);
      short8v hh, ll;
      split8(v, hh, ll);
      if (f == 0) { bh0 = hh; bl0 = ll; } else { bh1 = hh; bl1 = ll; }
    }
  }

  f32x4 acc[8];
#pragma unroll
  for (int r = 0; r < 8; ++r)
    acc[r] = *(const f32x4*)(b1g + r * 16 + q * 4);
#pragma unroll
  for (int r = 0; r < 8; ++r) {
    short8v ah0 = W1HI[(2 * r) * 64 + lane];
    short8v ah1 = W1HI[(2 * r + 1) * 64 + lane];
    short8v al0 = W1LO[(2 * r) * 64 + lane];
    short8v al1 = W1LO[(2 * r + 1) * 64 + lane];
    acc[r] = __builtin_amdgcn_mfma_f32_16x16x32_bf16(ah0, bh0, acc[r], 0, 0, 0);
    acc[r] = __builtin_amdgcn_mfma_f32_16x16x32_bf16(ah1, bh1, acc[r], 0, 0, 0);
    acc[r] = __builtin_amdgcn_mfma_f32_16x16x32_bf16(al0, bh0, acc[r], 0, 0, 0);
    acc[r] = __builtin_amdgcn_mfma_f32_16x16x32_bf16(al1, bh1, acc[r], 0, 0, 0);
    acc[r] = __builtin_amdgcn_mfma_f32_16x16x32_bf16(ah0, bl0, acc[r], 0, 0, 0);
    acc[r] = __builtin_amdgcn_mfma_f32_16x16x32_bf16(ah1, bl1, acc[r], 0, 0, 0);
  }
  float h1v[8][4];
#pragma unroll
  for (int r = 0; r < 8; ++r)
#pragma unroll
    for (int g = 0; g < 4; ++g) h1v[r][g] = fmaxf(acc[r][g], 0.f);

  short8v b2h[4], b2l[4];
#pragma unroll
  for (int f2 = 0; f2 < 4; ++f2) {
    float tmp[8];
#pragma unroll
    for (int j = 0; j < 8; ++j) tmp[j] = h1v[2 * f2 + (j >> 2)][j & 3];
    split8(tmp, b2h[f2], b2l[f2]);
  }

  f32x4 a20 = *(const f32x4*)(b2g + q * 4);
  f32x4 a21 = *(const f32x4*)(b2g + 16 + q * 4);
#pragma unroll
  for (int f2 = 0; f2 < 4; ++f2) {
    short8v ah = W2HI[f2 * 64 + lane];
    short8v al = W2LO[f2 * 64 + lane];
    a20 = __builtin_amdgcn_mfma_f32_16x16x32_bf16(ah, b2h[f2], a20, 0, 0, 0);
    a20 = __builtin_amdgcn_mfma_f32_16x16x32_bf16(al, b2h[f2], a20, 0, 0, 0);
    a20 = __builtin_amdgcn_mfma_f32_16x16x32_bf16(ah, b2l[f2], a20, 0, 0, 0);
    short8v ah1 = W2HI[(4 + f2) * 64 + lane];
    short8v al1 = W2LO[(4 + f2) * 64 + lane];
    a21 = __builtin_amdgcn_mfma_f32_16x16x32_bf16(ah1, b2h[f2], a21, 0, 0, 0);
    a21 = __builtin_amdgcn_mfma_f32_16x16x32_bf16(al1, b2h[f2], a21, 0, 0, 0);
    a21 = __builtin_amdgcn_mfma_f32_16x16x32_bf16(ah1, b2l[f2], a21, 0, 0, 0);
  }
  float h2v[8];
#pragma unroll
  for (int g = 0; g < 4; ++g) {
    h2v[g] = fmaxf(a20[g], 0.f);
    h2v[4 + g] = fmaxf(a21[g], 0.f);
  }

  // ---- 16-wide segmented inclusive sum along edge columns ----
  int dp = __shfl_up(d, 1, 16);
  bool head = (c == 0) || (dp != d);
  int seg = head ? c : 0;
#pragma unroll
  for (int off = 1; off < 16; off <<= 1) {
    int t = __shfl_up(seg, off, 16);
    if (c >= off) seg = max(seg, t);
  }
#pragma unroll
  for (int off = 1; off < 16; off <<= 1) {
    bool take = (c - off) >= seg;
#pragma unroll
    for (int k = 0; k < 8; ++k) {
      float t = __shfl_up(h2v[k], off, 16);
      if (take) h2v[k] += t;
    }
  }
  int dn = __shfl_down(d, 1, 16);
  bool tail = (c == 15) || (dn != d);
  if (tail) {
    float* hs = h2sum + (long)d * 32 + q * 4;
#pragma unroll
    for (int g = 0; g < 4; ++g) atomicAdd(&hs[g], h2v[g]);
#pragma unroll
    for (int g = 0; g < 4; ++g) atomicAdd(&hs[16 + g], h2v[4 + g]);
  }
}

// ------------------------- final gather / reduce -----------------------------
__global__ void __launch_bounds__(256) gather_kernel(
    const int2* __restrict__ csr, const int* __restrict__ offsets,
    const float* __restrict__ gp, const float* __restrict__ h2sum,
    const float* __restrict__ tW3, const float* __restrict__ tb3,
    float* __restrict__ out) {
  __shared__ float sW3[2048 + 64];
  for (int t = threadIdx.x; t < 2048; t += 256) sW3[t] = tW3[t];
  for (int t = threadIdx.x; t < 64; t += 256) sW3[2048 + t] = tb3[t];
  __syncthreads();
  int n = blockIdx.x * 8 + (threadIdx.x >> 5);
  int l = threadIdx.x & 31;
  int half = l >> 4, j4 = l & 15;
  int off = half * 64 + j4 * 4;
  int o0 = offsets[n], o1 = offsets[n + 1];
  int deg = o1 - o0;

  const float NEG = -3.402823466e38f;
  float4 mx = make_float4(NEG, NEG, NEG, NEG);
  float4 sm4 = make_float4(0.f, 0.f, 0.f, 0.f);
  for (int t = o0; t < o1; ++t) {
    int s = csr[t].x;
    float4 v = *(const float4*)(gp + (long)s * 128 + off);
    mx.x = fmaxf(mx.x, v.x); mx.y = fmaxf(mx.y, v.y);
    mx.z = fmaxf(mx.z, v.z); mx.w = fmaxf(mx.w, v.w);
    sm4.x += v.x; sm4.y += v.y; sm4.z += v.z; sm4.w += v.w;
  }

  float4 r;
  if (half == 0) {
    float4 a = *(const float4*)(out + (long)n * 128 + off);
    bool has = deg > 0;
    r.x = has ? a.x + mx.x : 0.f;
    r.y = has ? a.y + mx.y : 0.f;
    r.z = has ? a.z + mx.z : 0.f;
    r.w = has ? a.w + mx.w : 0.f;
  } else {
    int jj = j4 * 4;
    float w30 = 0.f, w31 = 0.f, w32 = 0.f, w33 = 0.f;
    const float* h2r = h2sum + (long)n * 32;
#pragma unroll
    for (int k = 0; k < 32; ++k) {
      float h = h2r[k];
      const float* wrow = &sW3[k * 64 + jj];
      w30 += h * wrow[0]; w31 += h * wrow[1];
      w32 += h * wrow[2]; w33 += h * wrow[3];
    }
    float dg = (float)deg;
    float inv = 1.f / fmaxf(dg, 1.f);
    r.x = (sm4.x + w30 + dg * sW3[2048 + jj + 0]) * inv;
    r.y = (sm4.y + w31 + dg * sW3[2048 + jj + 1]) * inv;
    r.z = (sm4.z + w32 + dg * sW3[2048 + jj + 2]) * inv;
    r.w = (sm4.w + w33 + dg * sW3[2048 + jj + 3]) * inv;
  }
  *(float4*)(out + (long)n * 128 + off) = r;
}

// ---------------------------------- launch -----------------------------------
extern "C" void kernel_launch(void* const* d_in, const int* in_sizes, int n_in,
                              void* d_out, int out_size, void* d_ws,
                              size_t ws_size, hipStream_t stream) {
  const float* x   = (const float*)d_in[0];
  const float* en  = (const float*)d_in[1];
  const int* src   = (const int*)d_in[2];
  const int* dst   = (const int*)d_in[3];
  const float* thW = (const float*)d_in[4];
  const float* thB = (const float*)d_in[5];
  const float* phW = (const float*)d_in[6];
  const float* phB = (const float*)d_in[7];
  const float* tW0 = (const float*)d_in[8];
  const float* tb0 = (const float*)d_in[9];
  const float* tW1 = (const float*)d_in[10];
  const float* tb1 = (const float*)d_in[11];
  const float* tW2 = (const float*)d_in[12];
  const float* tb2 = (const float*)d_in[13];
  const float* tW3 = (const float*)d_in[14];
  const float* tb3 = (const float*)d_in[15];
  const float* pW0 = (const float*)d_in[16];
  const float* pb0 = (const float*)d_in[17];
  const float* pW1 = (const float*)d_in[18];
  const float* pb1 = (const float*)d_in[19];
  const float* pW2 = (const float*)d_in[20];
  const float* pb2 = (const float*)d_in[21];
  const float* pW3 = (const float*)d_in[22];
  const float* pb3 = (const float*)d_in[23];

  float* out = (float*)d_out;
  float* ws  = (float*)d_ws;
  // ws layout (floats): gp[N*128], u[N*64], h2sum[N*32], wpack[30720], ints
  float* gp     = ws;                           // 6,400,000
  float* u      = ws + (long)N_NODES * 128;     // 3,200,000
  float* h2sum  = ws + (long)N_NODES * 192;     // 1,600,000
  float* wpf    = ws + (long)N_NODES * 224;     // 30,720 floats (61440 ushorts)
  ushort* wp    = (ushort*)wpf;
  int* iw       = (int*)(wpf + 30720);
  int2* csr     = (int2*)iw;                    // E pairs (src,dst)
  int* counts   = iw + 2 * N_EDGES;             // N (becomes cursor)
  int* offsets  = counts + N_NODES;             // N+1
  int* bsum     = offsets + N_NODES + 1;        // SCAN_NB
  // total ws ≈ 51.8 MB

  hipMemsetAsync(counts, 0, N_NODES * sizeof(int), stream);
  hipMemsetAsync(h2sum, 0, (size_t)N_NODES * 32 * sizeof(float), stream);
  combo1_kernel<<<C1_X + C1_CNT + C1_PACK, 256, 0, stream>>>(
      x, thW, thB, phW, phB, out, gp, dst, counts,
      tW1, tW2, tW0, pW0, pW1, pW2, pW3, wp);
  scan1_kernel<<<SCAN_NB, 1024, 0, stream>>>(counts, offsets, bsum);
  scan2_kernel<<<SCAN_NB, 1024, 0, stream>>>(bsum, offsets, counts);
  combo2_kernel<<<C2_EN + C2_SC, 512, 0, stream>>>(
      en, wp, pb0, pb1, pb2, pb3, u, gp, src, dst, counts, csr);
  mlp_edge_kernel<<<3125, 1024, 0, stream>>>(
      u, csr, tb0, tb1, tb2, wp, h2sum);
  gather_kernel<<<N_NODES / 8, 256, 0, stream>>>(
      csr, offsets, gp, h2sum, tW3, tb3, out);
}

// Round 15
// 311.841 us; speedup vs baseline: 1.0444x; 1.0442x over previous
//
#include <hip/hip_runtime.h>

#define N_NODES 50000
#define N_EDGES 800000

typedef __attribute__((ext_vector_type(8))) short short8v;
typedef __attribute__((ext_vector_type(4))) float f32x4;

__device__ __forceinline__ ushort bf16hi(float v) {
  return (ushort)(__float_as_uint(v) >> 16);
}

__device__ __forceinline__ void split8(const float v[8], short8v& hh, short8v& ll) {
#pragma unroll
  for (int j = 0; j < 8; ++j) {
    unsigned uv = __float_as_uint(v[j]);
    hh[j] = (short)(uv >> 16);
    float hf = __uint_as_float(uv & 0xFFFF0000u);
    ll[j] = (short)(__float_as_uint(v[j] - hf) >> 16);
  }
}

// ==================== combo1: node_x | count | pack ==========================
#define C1_X 196
#define C1_CNT 3125
#define C1_PACK 120

constexpr int XK_THT = 0;      // 2048
constexpr int XK_PHT = 2048;   // 2048
constexpr int XK_THB = 4096;   // 64
constexpr int XK_PHB = 4160;   // 64
constexpr int XK_SZ  = 4224;   // 16.9 KB

// wp layout (ushort offsets):
//  edge: W1sig1(tW1) hi [0,8192) lo [8192,16384)
//        W2sig(tW2)  hi [16384,20480) lo [20480,24576)
//        W0(tW0)     hi [24576,26624) lo [26624,28672)
//  node (contiguous 32768 block at 28672):
//        pW0 hi 28672 lo 30720 | pW1s1 hi 32768 lo 40960
//        pW2sig hi 49152 lo 53248 | pW3s3 hi 57344 lo 59392 | end 61440
__global__ void __launch_bounds__(256) combo1_kernel(
    const float* __restrict__ x,
    const float* __restrict__ thW, const float* __restrict__ thB,
    const float* __restrict__ phW, const float* __restrict__ phB,
    float* __restrict__ out, float* __restrict__ gp,
    const int* __restrict__ dst, int* __restrict__ counts,
    const float* __restrict__ tW1, const float* __restrict__ tW2,
    const float* __restrict__ tW0, const float* __restrict__ pW0,
    const float* __restrict__ pW1, const float* __restrict__ pW2,
    const float* __restrict__ pW3, ushort* __restrict__ wp) {
  const int b = blockIdx.x;
  const int tid = threadIdx.x;
  if (b < C1_X) {
    __shared__ __align__(16) float sm[XK_SZ];
    for (int t = tid; t < 2048; t += 256) {
      int j = t >> 5, k = t & 31;
      sm[XK_THT + t] = thW[k * 64 + j];
      sm[XK_PHT + t] = phW[k * 64 + j];
    }
    for (int t = tid; t < 64; t += 256) {
      sm[XK_THB + t] = thB[t];
      sm[XK_PHB + t] = phB[t];
    }
    __syncthreads();
    int n = b * 256 + tid;
    if (n >= N_NODES) return;

    float xv[32];
    {
      const float4* p = (const float4*)(x + (long)n * 32);
#pragma unroll
      for (int q = 0; q < 8; ++q) {
        float4 v = p[q];
        xv[q * 4 + 0] = v.x; xv[q * 4 + 1] = v.y;
        xv[q * 4 + 2] = v.z; xv[q * 4 + 3] = v.w;
      }
    }
    float* ao = out + (long)n * 128;
    float* go = gp + (long)n * 128;
    for (int j = 0; j < 64; ++j) {
      float dth = 0.f, dph = 0.f;
#pragma unroll
      for (int k = 0; k < 32; ++k) {
        dth += xv[k] * sm[XK_THT + j * 32 + k];
        dph += xv[k] * sm[XK_PHT + j * 32 + k];
      }
      ao[j] = sm[XK_THB + j] + dth;          // a
      go[j] = sm[XK_PHB + j] + dph - dth;    // g
    }
  } else if (b < C1_X + C1_CNT) {
    int e = (b - C1_X) * 256 + tid;
    if (e < N_EDGES) atomicAdd(&counts[dst[e]], 1);
  } else {
    int t = (b - C1_X - C1_CNT) * 256 + tid;
    if (t >= 30720) return;
    float v;
    int hi_off, lo_off;
    if (t < 8192) {
      // edge W1 sigma1 frags (same formula as node pW1s1, source tW1)
      int fi = t >> 9, lane = (t >> 3) & 63, j = t & 7;
      int r = fi >> 1, f = fi & 1;
      int row = r * 16 + (lane & 15);
      int sig = 32 * f + 16 * (j >> 2) + 4 * ((lane >> 4) & 3) + (j & 3);
      v = tW1[sig * 128 + row];
      hi_off = t; lo_off = 8192 + t;
    } else if (t < 12288) {
      // edge W2 sigma frags
      int t2 = t - 8192;
      int fi = t2 >> 9, lane = (t2 >> 3) & 63, j = t2 & 7;
      int tt = fi >> 2, f2 = fi & 3;
      int cc = tt * 16 + (lane & 15);
      int qq = (lane >> 4) & 3;
      int k2 = f2 * 32 + (j >> 2) * 16 + qq * 4 + (j & 3);
      v = tW2[k2 * 32 + cc];
      hi_off = 16384 + t2; lo_off = 20480 + t2;
    } else if (t < 14336) {
      // edge W0 (tW0) natural-K frags
      int t3 = t - 12288;
      int fi = t3 >> 9, lane = (t3 >> 3) & 63, j = t3 & 7;
      int row = fi * 16 + (lane & 15);
      int k = (lane >> 4) * 8 + j;
      v = tW0[k * 64 + row];
      hi_off = 24576 + t3; lo_off = 26624 + t3;
    } else if (t < 16384) {
      // node pW0 natural-K frags
      int t4 = t - 14336;
      int fi = t4 >> 9, lane = (t4 >> 3) & 63, j = t4 & 7;
      int row = fi * 16 + (lane & 15);
      int k = (lane >> 4) * 8 + j;
      v = pW0[k * 64 + row];
      hi_off = 28672 + t4; lo_off = 30720 + t4;
    } else if (t < 24576) {
      // node pW1 sigma1 frags
      int t5 = t - 16384;
      int fi = t5 >> 9, lane = (t5 >> 3) & 63, j = t5 & 7;
      int r = fi >> 1, f = fi & 1;
      int row = r * 16 + (lane & 15);
      int sig = 32 * f + 16 * (j >> 2) + 4 * ((lane >> 4) & 3) + (j & 3);
      v = pW1[sig * 128 + row];
      hi_off = 32768 + t5; lo_off = 40960 + t5;
    } else if (t < 28672) {
      // node pW2 sigma frags
      int t6 = t - 24576;
      int fi = t6 >> 9, lane = (t6 >> 3) & 63, j = t6 & 7;
      int tt = fi >> 2, f2 = fi & 3;
      int cc = tt * 16 + (lane & 15);
      int qq = (lane >> 4) & 3;
      int k2 = f2 * 32 + (j >> 2) * 16 + qq * 4 + (j & 3);
      v = pW2[k2 * 32 + cc];
      hi_off = 49152 + t6; lo_off = 53248 + t6;
    } else {
      // node pW3 sigma3 frags
      int t7 = t - 28672;
      int fi = t7 >> 9, lane = (t7 >> 3) & 63, j = t7 & 7;
      int row = fi * 16 + (lane & 15);
      int sig = 16 * (j >> 2) + 4 * ((lane >> 4) & 3) + (j & 3);
      v = pW3[sig * 64 + row];
      hi_off = 57344 + t7; lo_off = 59392 + t7;
    }
    ushort h = bf16hi(v);
    float hf = __uint_as_float((unsigned)h << 16);
    ushort l = bf16hi(v - hf);
    wp[hi_off] = h;
    wp[lo_off] = l;
  }
}

// ------------------------------- scan --------------------------------------
#define SCAN_NB ((N_NODES + 1023) / 1024)   // 49

__global__ void __launch_bounds__(1024) scan1_kernel(
    const int* __restrict__ counts, int* __restrict__ offsets,
    int* __restrict__ bsum) {
  __shared__ int wsum[16];
  int t = threadIdx.x, b = blockIdx.x;
  int idx = b * 1024 + t;
  int c = (idx < N_NODES) ? counts[idx] : 0;
  int lane = t & 63, w = t >> 6;
  int v = c;
#pragma unroll
  for (int off = 1; off < 64; off <<= 1) {
    int tt = __shfl_up(v, off);
    if (lane >= off) v += tt;
  }
  if (lane == 63) wsum[w] = v;
  __syncthreads();
  int wpre = 0;
#pragma unroll
  for (int i = 0; i < 16; ++i) {
    int tt = wsum[i];
    if (i < w) wpre += tt;
  }
  int incl = v + wpre;
  if (idx < N_NODES) offsets[idx] = incl - c;   // exclusive-within-block
  if (t == 1023) bsum[b] = incl;                // block total
}

__global__ void __launch_bounds__(1024) scan2_kernel(
    const int* __restrict__ bsum, int* __restrict__ offsets,
    int* __restrict__ counts) {
  __shared__ int sb[SCAN_NB];
  int t = threadIdx.x, b = blockIdx.x;
  if (t < SCAN_NB) sb[t] = bsum[t];
  __syncthreads();
  int bpre = 0;
#pragma unroll
  for (int i = 0; i < SCAN_NB; ++i) {
    int tt = sb[i];
    if (i < b) bpre += tt;
  }
  int idx = b * 1024 + t;
  if (idx < N_NODES) {
    int v = offsets[idx] + bpre;
    offsets[idx] = v;
    counts[idx] = v;          // cursor for scatter
  }
  if (b == 0 && t == 0) offsets[N_NODES] = N_EDGES;
}

// =================== combo2: node_en (MFMA) | scatter ========================
#define C2_EN 391
#define C2_SC 1563

__global__ void __launch_bounds__(512) combo2_kernel(
    const float* __restrict__ en, const ushort* __restrict__ wp,
    const float* __restrict__ pb0, const float* __restrict__ pb1,
    const float* __restrict__ pb2, const float* __restrict__ pb3,
    float* __restrict__ gp,
    const int* __restrict__ src, const int* __restrict__ dst,
    int* __restrict__ cursor, int2* __restrict__ csr) {
  const int b = blockIdx.x;
  const int tid = threadIdx.x;
  if (b < C2_EN) {
    __shared__ __align__(16) ushort lds[32768];   // 64 KB (node frag block)
    {
      const uint4* s4 = (const uint4*)(wp + 28672);
      uint4* d4 = (uint4*)lds;
      for (int i = tid; i < 4096; i += 512) d4[i] = s4[i];
    }
    __syncthreads();
    const int lane = tid & 63, q = lane >> 4, c = lane & 15, wv = tid >> 6;
    const int n = (b * 8 + wv) * 16 + c;
    const bool valid = n < N_NODES;

    float env[8];
#pragma unroll
    for (int j = 0; j < 8; ++j) env[j] = 0.f;
    if (valid) {
      const float4* p = (const float4*)(en + (long)n * 32 + q * 8);
      float4 e0 = p[0], e1 = p[1];
      env[0] = e0.x; env[1] = e0.y; env[2] = e0.z; env[3] = e0.w;
      env[4] = e1.x; env[5] = e1.y; env[6] = e1.z; env[7] = e1.w;
    }
    short8v beh, bel;
    split8(env, beh, bel);

    const short8v* PW0H = (const short8v*)(lds);
    const short8v* PW0L = (const short8v*)(lds + 2048);
    const short8v* NW1H = (const short8v*)(lds + 4096);
    const short8v* NW1L = (const short8v*)(lds + 12288);
    const short8v* NW2H = (const short8v*)(lds + 20480);
    const short8v* NW2L = (const short8v*)(lds + 24576);
    const short8v* NW3H = (const short8v*)(lds + 28672);
    const short8v* NW3L = (const short8v*)(lds + 30720);

    float h0v[4][4];
#pragma unroll
    for (int t = 0; t < 4; ++t) {
      f32x4 a = *(const f32x4*)(pb0 + t * 16 + q * 4);
      short8v ah = PW0H[t * 64 + lane], al = PW0L[t * 64 + lane];
      a = __builtin_amdgcn_mfma_f32_16x16x32_bf16(ah, beh, a, 0, 0, 0);
      a = __builtin_amdgcn_mfma_f32_16x16x32_bf16(al, beh, a, 0, 0, 0);
      a = __builtin_amdgcn_mfma_f32_16x16x32_bf16(ah, bel, a, 0, 0, 0);
#pragma unroll
      for (int g = 0; g < 4; ++g) h0v[t][g] = fmaxf(a[g], 0.f);
    }

    short8v b1h[2], b1l[2];
#pragma unroll
    for (int f = 0; f < 2; ++f) {
      float tmp[8];
#pragma unroll
      for (int j = 0; j < 8; ++j) tmp[j] = h0v[2 * f + (j >> 2)][j & 3];
      split8(tmp, b1h[f], b1l[f]);
    }

    float h1v[8][4];
#pragma unroll
    for (int r = 0; r < 8; ++r) {
      f32x4 a = *(const f32x4*)(pb1 + r * 16 + q * 4);
#pragma unroll
      for (int f = 0; f < 2; ++f) {
        short8v ah = NW1H[(r * 2 + f) * 64 + lane];
        short8v al = NW1L[(r * 2 + f) * 64 + lane];
        a = __builtin_amdgcn_mfma_f32_16x16x32_bf16(ah, b1h[f], a, 0, 0, 0);
        a = __builtin_amdgcn_mfma_f32_16x16x32_bf16(al, b1h[f], a, 0, 0, 0);
        a = __builtin_amdgcn_mfma_f32_16x16x32_bf16(ah, b1l[f], a, 0, 0, 0);
      }
#pragma unroll
      for (int g = 0; g < 4; ++g) h1v[r][g] = fmaxf(a[g], 0.f);
    }

    short8v b2h[4], b2l[4];
#pragma unroll
    for (int f2 = 0; f2 < 4; ++f2) {
      float tmp[8];
#pragma unroll
      for (int j = 0; j < 8; ++j) tmp[j] = h1v[2 * f2 + (j >> 2)][j & 3];
      split8(tmp, b2h[f2], b2l[f2]);
    }

    float h2v[2][4];
#pragma unroll
    for (int tt = 0; tt < 2; ++tt) {
      f32x4 a = *(const f32x4*)(pb2 + tt * 16 + q * 4);
#pragma unroll
      for (int f2 = 0; f2 < 4; ++f2) {
        short8v ah = NW2H[(tt * 4 + f2) * 64 + lane];
        short8v al = NW2L[(tt * 4 + f2) * 64 + lane];
        a = __builtin_amdgcn_mfma_f32_16x16x32_bf16(ah, b2h[f2], a, 0, 0, 0);
        a = __builtin_amdgcn_mfma_f32_16x16x32_bf16(al, b2h[f2], a, 0, 0, 0);
        a = __builtin_amdgcn_mfma_f32_16x16x32_bf16(ah, b2l[f2], a, 0, 0, 0);
      }
#pragma unroll
      for (int g = 0; g < 4; ++g) h2v[tt][g] = fmaxf(a[g], 0.f);
    }

    short8v b3h, b3l;
    {
      float tmp[8];
#pragma unroll
      for (int j = 0; j < 8; ++j) tmp[j] = h2v[j >> 2][j & 3];
      split8(tmp, b3h, b3l);
    }

#pragma unroll
    for (int t = 0; t < 4; ++t) {
      f32x4 a = *(const f32x4*)(pb3 + t * 16 + q * 4);
      short8v ah = NW3H[t * 64 + lane], al = NW3L[t * 64 + lane];
      a = __builtin_amdgcn_mfma_f32_16x16x32_bf16(ah, b3h, a, 0, 0, 0);
      a = __builtin_amdgcn_mfma_f32_16x16x32_bf16(al, b3h, a, 0, 0, 0);
      a = __builtin_amdgcn_mfma_f32_16x16x32_bf16(ah, b3l, a, 0, 0, 0);
      if (valid) *(f32x4*)(gp + (long)n * 128 + 64 + t * 16 + q * 4) = a;
    }
  } else {
    int e = (b - C2_EN) * 512 + tid;
    if (e >= N_EDGES) return;
    int d = dst[e];
    int slot = atomicAdd(&cursor[d], 1);
    csr[slot] = make_int2(src[e], d);
  }
}

// ---- per-edge theta MLP (all 3 layers) via split-bf16 MFMA, en-direct -------
// h0 = relu(W0^T(en[d]-en[s]) + b0) computed in-kernel (K=32 MFMA stage);
// sigma1 links W0-output C-layout to GEMM1's B lane-locally; sigma links
// GEMM1 to GEMM2. Random gather = 2 x 128B en rows (was 2 x 256B u rows).
__global__ void __launch_bounds__(1024) mlp_edge_kernel(
    const float* __restrict__ en,
    const int2* __restrict__ csr,
    const float* __restrict__ b0g, const float* __restrict__ b1g,
    const float* __restrict__ b2g,
    const ushort* __restrict__ wp,
    float* __restrict__ h2sum) {
  __shared__ __align__(16) ushort lds[28672];   // 56 KB
  {
    const uint4* s4 = (const uint4*)wp;
    uint4* d4 = (uint4*)lds;
    for (int i = threadIdx.x; i < 3584; i += 1024) d4[i] = s4[i];
  }
  __syncthreads();

  // bijective XCD swizzle (nwg=3125, q=390, r=5; m204 form)
  const int orig = blockIdx.x;
  const int xcd = orig & 7, loc = orig >> 3;
  const int blk = (xcd < 5) ? xcd * 391 + loc
                            : 5 * 391 + (xcd - 5) * 390 + loc;

  const int lane = threadIdx.x & 63;
  const int q = lane >> 4, c = lane & 15;
  const int wv = threadIdx.x >> 6;
  const int e = (blk * 16 + wv) * 16 + c;   // exact fit: 3125*256=800000
  const int2 pr = csr[e];
  const int s = pr.x, d = pr.y;

  const short8v* W1HI = (const short8v*)(lds);
  const short8v* W1LO = (const short8v*)(lds + 8192);
  const short8v* W2HI = (const short8v*)(lds + 16384);
  const short8v* W2LO = (const short8v*)(lds + 20480);
  const short8v* W0H  = (const short8v*)(lds + 24576);
  const short8v* W0L  = (const short8v*)(lds + 26624);

  // ---- den frag: en[d] - en[s], this lane's 8-float k-slice ----
  short8v dh, dl;
  {
    const float4* pd = (const float4*)(en + (long)d * 32 + q * 8);
    const float4* ps = (const float4*)(en + (long)s * 32 + q * 8);
    float4 a0 = pd[0], a1 = pd[1], b0 = ps[0], b1 = ps[1];
    float v[8];
    v[0] = a0.x - b0.x; v[1] = a0.y - b0.y;
    v[2] = a0.z - b0.z; v[3] = a0.w - b0.w;
    v[4] = a1.x - b1.x; v[5] = a1.y - b1.y;
    v[6] = a1.z - b1.z; v[7] = a1.w - b1.w;
    split8(v, dh, dl);
  }

  // ---- W0 stage: h0 = relu(W0^T den + b0), 4 row-tiles, K=32 ----
  float h0v[4][4];
#pragma unroll
  for (int t = 0; t < 4; ++t) {
    f32x4 a = *(const f32x4*)(b0g + t * 16 + q * 4);
    short8v ah = W0H[t * 64 + lane], al = W0L[t * 64 + lane];
    a = __builtin_amdgcn_mfma_f32_16x16x32_bf16(ah, dh, a, 0, 0, 0);
    a = __builtin_amdgcn_mfma_f32_16x16x32_bf16(al, dh, a, 0, 0, 0);
    a = __builtin_amdgcn_mfma_f32_16x16x32_bf16(ah, dl, a, 0, 0, 0);
#pragma unroll
    for (int g = 0; g < 4; ++g) h0v[t][g] = fmaxf(a[g], 0.f);
  }

  // ---- B1 frags via sigma1 (lane-local) ----
  short8v b1h[2], b1l[2];
#pragma unroll
  for (int f = 0; f < 2; ++f) {
    float tmp[8];
#pragma unroll
    for (int j = 0; j < 8; ++j) tmp[j] = h0v[2 * f + (j >> 2)][j & 3];
    split8(tmp, b1h[f], b1l[f]);
  }

  // ---- GEMM1: h1 = relu(W1^T h0 + b1), 8 row-tiles x 2 k-frags ----
  float h1v[8][4];
#pragma unroll
  for (int r = 0; r < 8; ++r) {
    f32x4 a = *(const f32x4*)(b1g + r * 16 + q * 4);
#pragma unroll
    for (int f = 0; f < 2; ++f) {
      short8v ah = W1HI[(r * 2 + f) * 64 + lane];
      short8v al = W1LO[(r * 2 + f) * 64 + lane];
      a = __builtin_amdgcn_mfma_f32_16x16x32_bf16(ah, b1h[f], a, 0, 0, 0);
      a = __builtin_amdgcn_mfma_f32_16x16x32_bf16(al, b1h[f], a, 0, 0, 0);
      a = __builtin_amdgcn_mfma_f32_16x16x32_bf16(ah, b1l[f], a, 0, 0, 0);
    }
#pragma unroll
    for (int g = 0; g < 4; ++g) h1v[r][g] = fmaxf(a[g], 0.f);
  }

  // ---- B2 frags via sigma (lane-local) ----
  short8v b2h[4], b2l[4];
#pragma unroll
  for (int f2 = 0; f2 < 4; ++f2) {
    float tmp[8];
#pragma unroll
    for (int j = 0; j < 8; ++j) tmp[j] = h1v[2 * f2 + (j >> 2)][j & 3];
    split8(tmp, b2h[f2], b2l[f2]);
  }

  // ---- GEMM2: 2 out-tiles x 4 k-frags x 3 split ----
  f32x4 a20 = *(const f32x4*)(b2g + q * 4);
  f32x4 a21 = *(const f32x4*)(b2g + 16 + q * 4);
#pragma unroll
  for (int f2 = 0; f2 < 4; ++f2) {
    short8v ah = W2HI[f2 * 64 + lane];
    short8v al = W2LO[f2 * 64 + lane];
    a20 = __builtin_amdgcn_mfma_f32_16x16x32_bf16(ah, b2h[f2], a20, 0, 0, 0);
    a20 = __builtin_amdgcn_mfma_f32_16x16x32_bf16(al, b2h[f2], a20, 0, 0, 0);
    a20 = __builtin_amdgcn_mfma_f32_16x16x32_bf16(ah, b2l[f2], a20, 0, 0, 0);
    short8v ah1 = W2HI[(4 + f2) * 64 + lane];
    short8v al1 = W2LO[(4 + f2) * 64 + lane];
    a21 = __builtin_amdgcn_mfma_f32_16x16x32_bf16(ah1, b2h[f2], a21, 0, 0, 0);
    a21 = __builtin_amdgcn_mfma_f32_16x16x32_bf16(al1, b2h[f2], a21, 0, 0, 0);
    a21 = __builtin_amdgcn_mfma_f32_16x16x32_bf16(ah1, b2l[f2], a21, 0, 0, 0);
  }
  float h2v[8];
#pragma unroll
  for (int g = 0; g < 4; ++g) {
    h2v[g] = fmaxf(a20[g], 0.f);
    h2v[4 + g] = fmaxf(a21[g], 0.f);
  }

  // ---- 16-wide segmented inclusive sum along edge columns ----
  int dp = __shfl_up(d, 1, 16);
  bool head = (c == 0) || (dp != d);
  int seg = head ? c : 0;
#pragma unroll
  for (int off = 1; off < 16; off <<= 1) {
    int t = __shfl_up(seg, off, 16);
    if (c >= off) seg = max(seg, t);
  }
#pragma unroll
  for (int off = 1; off < 16; off <<= 1) {
    bool take = (c - off) >= seg;
#pragma unroll
    for (int k = 0; k < 8; ++k) {
      float t = __shfl_up(h2v[k], off, 16);
      if (take) h2v[k] += t;
    }
  }
  int dn = __shfl_down(d, 1, 16);
  bool tail = (c == 15) || (dn != d);
  if (tail) {
    float* hs = h2sum + (long)d * 32 + q * 4;
#pragma unroll
    for (int g = 0; g < 4; ++g) atomicAdd(&hs[g], h2v[g]);
#pragma unroll
    for (int g = 0; g < 4; ++g) atomicAdd(&hs[16 + g], h2v[4 + g]);
  }
}

// ------------------------- final gather / reduce -----------------------------
__global__ void __launch_bounds__(256) gather_kernel(
    const int2* __restrict__ csr, const int* __restrict__ offsets,
    const float* __restrict__ gp, const float* __restrict__ h2sum,
    const float* __restrict__ tW3, const float* __restrict__ tb3,
    float* __restrict__ out) {
  __shared__ float sW3[2048 + 64];
  for (int t = threadIdx.x; t < 2048; t += 256) sW3[t] = tW3[t];
  for (int t = threadIdx.x; t < 64; t += 256) sW3[2048 + t] = tb3[t];
  __syncthreads();
  int n = blockIdx.x * 8 + (threadIdx.x >> 5);
  int l = threadIdx.x & 31;
  int half = l >> 4, j4 = l & 15;
  int off = half * 64 + j4 * 4;
  int o0 = offsets[n], o1 = offsets[n + 1];
  int deg = o1 - o0;

  const float NEG = -3.402823466e38f;
  float4 mx = make_float4(NEG, NEG, NEG, NEG);
  float4 sm4 = make_float4(0.f, 0.f, 0.f, 0.f);
  for (int t = o0; t < o1; ++t) {
    int s = csr[t].x;
    float4 v = *(const float4*)(gp + (long)s * 128 + off);
    mx.x = fmaxf(mx.x, v.x); mx.y = fmaxf(mx.y, v.y);
    mx.z = fmaxf(mx.z, v.z); mx.w = fmaxf(mx.w, v.w);
    sm4.x += v.x; sm4.y += v.y; sm4.z += v.z; sm4.w += v.w;
  }

  float4 r;
  if (half == 0) {
    float4 a = *(const float4*)(out + (long)n * 128 + off);
    bool has = deg > 0;
    r.x = has ? a.x + mx.x : 0.f;
    r.y = has ? a.y + mx.y : 0.f;
    r.z = has ? a.z + mx.z : 0.f;
    r.w = has ? a.w + mx.w : 0.f;
  } else {
    int jj = j4 * 4;
    float w30 = 0.f, w31 = 0.f, w32 = 0.f, w33 = 0.f;
    const float* h2r = h2sum + (long)n * 32;
#pragma unroll
    for (int k = 0; k < 32; ++k) {
      float h = h2r[k];
      const float* wrow = &sW3[k * 64 + jj];
      w30 += h * wrow[0]; w31 += h * wrow[1];
      w32 += h * wrow[2]; w33 += h * wrow[3];
    }
    float dg = (float)deg;
    float inv = 1.f / fmaxf(dg, 1.f);
    r.x = (sm4.x + w30 + dg * sW3[2048 + jj + 0]) * inv;
    r.y = (sm4.y + w31 + dg * sW3[2048 + jj + 1]) * inv;
    r.z = (sm4.z + w32 + dg * sW3[2048 + jj + 2]) * inv;
    r.w = (sm4.w + w33 + dg * sW3[2048 + jj + 3]) * inv;
  }
  *(float4*)(out + (long)n * 128 + off) = r;
}

// ---------------------------------- launch -----------------------------------
extern "C" void kernel_launch(void* const* d_in, const int* in_sizes, int n_in,
                              void* d_out, int out_size, void* d_ws,
                              size_t ws_size, hipStream_t stream) {
  const float* x   = (const float*)d_in[0];
  const float* en  = (const float*)d_in[1];
  const int* src   = (const int*)d_in[2];
  const int* dst   = (const int*)d_in[3];
  const float* thW = (const float*)d_in[4];
  const float* thB = (const float*)d_in[5];
  const float* phW = (const float*)d_in[6];
  const float* phB = (const float*)d_in[7];
  const float* tW0 = (const float*)d_in[8];
  const float* tb0 = (const float*)d_in[9];
  const float* tW1 = (const float*)d_in[10];
  const float* tb1 = (const float*)d_in[11];
  const float* tW2 = (const float*)d_in[12];
  const float* tb2 = (const float*)d_in[13];
  const float* tW3 = (const float*)d_in[14];
  const float* tb3 = (const float*)d_in[15];
  const float* pW0 = (const float*)d_in[16];
  const float* pb0 = (const float*)d_in[17];
  const float* pW1 = (const float*)d_in[18];
  const float* pb1 = (const float*)d_in[19];
  const float* pW2 = (const float*)d_in[20];
  const float* pb2 = (const float*)d_in[21];
  const float* pW3 = (const float*)d_in[22];
  const float* pb3 = (const float*)d_in[23];

  float* out = (float*)d_out;
  float* ws  = (float*)d_ws;
  // ws layout (floats): gp[N*128], h2sum[N*32], wpack[30720], ints
  float* gp     = ws;                           // 6,400,000
  float* h2sum  = ws + (long)N_NODES * 128;     // 1,600,000
  float* wpf    = ws + (long)N_NODES * 160;     // 30,720 floats (61440 ushorts)
  ushort* wp    = (ushort*)wpf;
  int* iw       = (int*)(wpf + 30720);
  int2* csr     = (int2*)iw;                    // E pairs (src,dst)
  int* counts   = iw + 2 * N_EDGES;             // N (becomes cursor)
  int* offsets  = counts + N_NODES;             // N+1
  int* bsum     = offsets + N_NODES + 1;        // SCAN_NB
  // total ws ≈ 39 MB

  hipMemsetAsync(counts, 0, N_NODES * sizeof(int), stream);
  hipMemsetAsync(h2sum, 0, (size_t)N_NODES * 32 * sizeof(float), stream);
  combo1_kernel<<<C1_X + C1_CNT + C1_PACK, 256, 0, stream>>>(
      x, thW, thB, phW, phB, out, gp, dst, counts,
      tW1, tW2, tW0, pW0, pW1, pW2, pW3, wp);
  scan1_kernel<<<SCAN_NB, 1024, 0, stream>>>(counts, offsets, bsum);
  scan2_kernel<<<SCAN_NB, 1024, 0, stream>>>(bsum, offsets, counts);
  combo2_kernel<<<C2_EN + C2_SC, 512, 0, stream>>>(
      en, wp, pb0, pb1, pb2, pb3, gp, src, dst, counts, csr);
  mlp_edge_kernel<<<3125, 1024, 0, stream>>>(
      en, csr, tb0, tb1, tb2, wp, h2sum);
  gather_kernel<<<N_NODES / 8, 256, 0, stream>>>(
      csr, offsets, gp, h2sum, tW3, tb3, out);
}